// Round 4
// baseline (314.668 us; speedup 1.0000x reference)
//
#include <hip/hip_runtime.h>
#include <math.h>

#define NIMG 4
#define NCLS 15
#define HW 65536
#define NANG 90
#define KTOP 400
#define POSTN 100
#define NBINS 4096
#define CAP 4096
#define NBLK 128            // k_hist blocks per image
#define SBUF 512            // per-block stage buffer (expected ~92 entries/block)
#define FLOOR_VAL (1434.0f / 4096.0f)   // bit-exact: comb >= 1434/4096  <=>  bin >= 1434

// ---- workspace layout (bytes); NO pre-zeroing needed (every byte read is written) ----
#define CNTB_OFF   0                      // 4*128*4 = 2048
#define SKEY_OFF   2048                   // 4*400*8 = 12800
#define COR_OFF    14848                  // 4*400*8*4 = 51200
#define AREA_OFF   66048                  // 6400 each below
#define LAB_OFF    72448
#define SC_OFF     78848
#define VAL_OFF    85248
#define CCX_OFF    91648
#define CCY_OFF    98048
#define CRAD_OFF   104448
#define STAGE_OFF  110848                 // 4*128*512*8 = 2 MB -> ends 2208000

__device__ __forceinline__ float sigmoidf(float x) {
    return 1.0f / (1.0f + expf(-x));
}

// ---------------- K1: stage candidates with comb >= FLOOR into block-private regions ----
// No histogram, no global atomics, no pre-zeroed state.
__global__ __launch_bounds__(256)
void k_hist(const float* __restrict__ cls, const float* __restrict__ ctr,
            int* __restrict__ cnt_blk, unsigned long long* __restrict__ stage) {
    __shared__ unsigned long long sbuf[SBUF];
    __shared__ int scount;
    const int n = blockIdx.y;
    const int bx = blockIdx.x;
    const int p2 = (bx * 256 + threadIdx.x) * 2;
    if (threadIdx.x == 0) scount = 0;
    __syncthreads();
    float2 cv2 = *(const float2*)(ctr + n * HW + p2);
    float cv[2] = {sigmoidf(cv2.x), sigmoidf(cv2.y)};
    for (int j = 0; j < NCLS; ++j) {
        float2 s2 = *(const float2*)(cls + (size_t)(n * NCLS + j) * HW + p2);
        float sv[2] = {s2.x, s2.y};
#pragma unroll
        for (int e = 0; e < 2; ++e) {
            float s = sigmoidf(sv[e]);
            float comb = s * cv[e];
            if (comb >= FLOOR_VAL) {          // implies s > 0.05 (comb <= s)
                int m = atomicAdd(&scount, 1);
                if (m < SBUF) {
                    unsigned int fb  = __float_as_uint(comb);
                    unsigned int idx = (unsigned int)((p2 + e) * NCLS + j);
                    sbuf[m] = ((unsigned long long)fb << 32) |
                              (unsigned long long)(~idx);
                }
            }
        }
    }
    __syncthreads();
    int c = scount;
    int cc = c > SBUF ? SBUF : c;
    if (threadIdx.x == 0)
        cnt_blk[n * NBLK + bx] = (c > SBUF) ? (cc | (1 << 31)) : cc;
    unsigned long long* rp = stage + (size_t)(n * NBLK + bx) * SBUF;
    for (int m = threadIdx.x; m < cc; m += 256) rp[m] = sbuf[m];
}

// ---------------- K2: staged histogram -> exact threshold -> filter -> bitonic top-400 ---
// 1 block per image. Fallback full-rescan path kept for unconditional correctness.
__global__ __launch_bounds__(256)
void k_selstage(const unsigned long long* __restrict__ stage,
                const int* __restrict__ cnt_blk,
                const float* __restrict__ cls, const float* __restrict__ ctr,
                unsigned long long* __restrict__ skey) {
    const int n = blockIdx.x;
    __shared__ unsigned long long key[CAP];    // 32 KB
    __shared__ int hist[NBINS];                // 16 KB
    __shared__ int cbc[NBLK];
    __shared__ int part[256];
    __shared__ int s_t, s_c, s_tot, s_ovf;
    const int tid = threadIdx.x;
    if (tid == 0) { s_t = 0; s_c = 0; s_tot = 0; s_ovf = 0; }
    for (int b = tid; b < NBINS; b += 256) hist[b] = 0;
    __syncthreads();
    if (tid < NBLK) {
        int v = cnt_blk[n * NBLK + tid];
        int c = v & 0x7fffffff;
        cbc[tid] = c;
        atomicAdd(&s_tot, c);
        if (v < 0) atomicOr(&s_ovf, 1);
    }
    __syncthreads();
    const int r  = tid >> 1;                   // region 0..127 (2 threads per region)
    const int m0 = tid & 1;
    const bool fb = (s_ovf != 0) || (s_tot < KTOP);
    if (!fb) {
        // histogram over staged entries (staged hist == full hist above FLOOR;
        // total >= 400 guarantees exact t >= FLOOR)
        const unsigned long long* rp = stage + (size_t)(n * NBLK + r) * SBUF;
        const int c = cbc[r];
        for (int m = m0; m < c; m += 2) {
            float comb = __uint_as_float((unsigned int)(rp[m] >> 32));
            int b = (int)(comb * 4096.0f);
            b = b < 0 ? 0 : (b > NBINS - 1 ? NBINS - 1 : b);
            atomicAdd(&hist[b], 1);
        }
    } else {
        // fallback: full histogram of image n (never taken on healthy margins)
        for (int j = 0; j < NCLS; ++j) {
            for (int pos = tid; pos < HW; pos += 256) {
                float s = sigmoidf(cls[(size_t)(n * NCLS + j) * HW + pos]);
                if (s > 0.05f) {
                    float comb = s * sigmoidf(ctr[n * HW + pos]);
                    int b = (int)(comb * 4096.0f);
                    b = b < 0 ? 0 : (b > NBINS - 1 ? NBINS - 1 : b);
                    atomicAdd(&hist[b], 1);
                }
            }
        }
    }
    __syncthreads();
    // exact threshold via segment suffix-scan (verbatim round-3 logic, LDS hist)
    {
        int s = 0;
        int base = tid * 16;
        for (int b = 0; b < 16; ++b) s += hist[base + b];
        part[tid] = s;
        __syncthreads();
        for (int off = 1; off < 256; off <<= 1) {
            int v = part[tid] + ((tid + off < 256) ? part[tid + off] : 0);
            __syncthreads();
            part[tid] = v;
            __syncthreads();
        }
        int sg = tid;
        int suf = part[sg];
        int above = (sg == 255) ? 0 : part[sg + 1];
        if (suf >= KTOP && above < KTOP) {
            int a2 = above, t = sg * 16;
            for (int b = sg * 16 + 15; b >= sg * 16; --b) {
                a2 += hist[b];
                if (a2 >= KTOP) { t = b; break; }
            }
            s_t = t;            // exactly one thread writes
        }
        __syncthreads();
    }
    const int t = s_t;
    if (!fb) {
        const unsigned long long* rp = stage + (size_t)(n * NBLK + r) * SBUF;
        const int c = cbc[r];
        for (int m = m0; m < c; m += 2) {
            unsigned long long kk = rp[m];
            float comb = __uint_as_float((unsigned int)(kk >> 32));
            int b = (int)(comb * 4096.0f);
            b = b < 0 ? 0 : (b > NBINS - 1 ? NBINS - 1 : b);
            if (b >= t) {
                int pos = atomicAdd(&s_c, 1);
                if (pos < CAP) key[pos] = kk;
            }
        }
    } else {
        for (int j = 0; j < NCLS; ++j) {
            for (int pos = tid; pos < HW; pos += 256) {
                float s = sigmoidf(cls[(size_t)(n * NCLS + j) * HW + pos]);
                if (s > 0.05f) {
                    float comb = s * sigmoidf(ctr[n * HW + pos]);
                    int b = (int)(comb * 4096.0f);
                    b = b < 0 ? 0 : (b > NBINS - 1 ? NBINS - 1 : b);
                    if (b >= t) {
                        int pos2 = atomicAdd(&s_c, 1);
                        if (pos2 < CAP) {
                            unsigned int fbits = __float_as_uint(comb);
                            unsigned int idx = (unsigned int)(pos * NCLS + j);
                            key[pos2] = ((unsigned long long)fbits << 32) |
                                        (unsigned long long)(~idx);
                        }
                    }
                }
            }
        }
    }
    __syncthreads();
    int c = s_c;
    if (c > CAP) c = CAP;
    int S = 512;
    while (S < c) S <<= 1;
    for (int i = tid; i < S; i += 256)
        if (i >= c) key[i] = 0ULL;
    __syncthreads();
    for (int k = 2; k <= S; k <<= 1) {
        for (int j = k >> 1; j > 0; j >>= 1) {
            for (int i = tid; i < S; i += 256) {
                int l = i ^ j;
                if (l > i) {
                    unsigned long long a = key[i], b = key[l];
                    bool up = ((i & k) == 0);
                    if ((a > b) == up) { key[i] = b; key[l] = a; }
                }
            }
            __syncthreads();
        }
    }
    for (int r2 = tid; r2 < KTOP; r2 += 256)
        skey[n * KTOP + r2] = key[S - 1 - r2];
}

// ---------------- K3: per-candidate decode (one wave each; round-0 verified) ----------
__global__ __launch_bounds__(64)
void k_decode(const unsigned long long* __restrict__ skey,
              const float* __restrict__ reg, const float* __restrict__ ang,
              const float* __restrict__ anchors,
              float* __restrict__ cor, float* __restrict__ area, int* __restrict__ lab,
              float* __restrict__ sc, int* __restrict__ val,
              float* __restrict__ ccx, float* __restrict__ ccy, float* __restrict__ crad) {
#pragma clang fp contract(off)
    const int r = blockIdx.x;
    const int n = blockIdx.y;
    const int l = threadIdx.x;
    const int base = n * KTOP + r;
    unsigned long long kk = skey[base];
    if (kk == 0ULL) {
        if (l == 0) {
            val[base] = 0; sc[base] = 0.0f; lab[base] = 0; area[base] = 0.0f;
            ccx[base] = 0.0f; ccy[base] = 0.0f; crad[base] = 0.0f;
            for (int q = 0; q < 8; ++q) cor[base * 8 + q] = 0.0f;
        }
        return;
    }
    unsigned int idx = ~((unsigned int)kk);
    int loc = (int)(idx / 15u);
    // angle argmax (first max) across the wave
    const float* ap = ang + ((size_t)n * NANG) * HW + loc;
    float bv = -INFINITY; int bb = 1000;
    for (int b = l; b < NANG; b += 64) {
        float v = ap[(size_t)b * HW];
        if (v > bv) { bv = v; bb = b; }   // b ascending per lane: keeps first max
    }
    for (int off = 32; off > 0; off >>= 1) {
        float ov = __shfl_down(bv, off);
        int   ob = __shfl_down(bb, off);
        if (ov > bv || (ov == bv && ob < bb)) { bv = ov; bb = ob; }
    }
    if (l == 0) {
        int cl = (int)(idx % 15u);
        float topv = __uint_as_float((unsigned int)(kk >> 32));
        const float* rp = reg + ((size_t)n * 4) * HW + loc;
        float dx = rp[0] / 10.0f;
        float dy = rp[HW] / 10.0f;
        float dw = rp[2 * (size_t)HW] / 5.0f;
        float dh = rp[3 * (size_t)HW] / 5.0f;
        dw = fminf(fmaxf(dw, -10.0f), 4.0f);
        dh = fminf(fmaxf(dh, -10.0f), 4.0f);
        const float* an = anchors + ((size_t)n * HW + loc) * 5;
        float acx = an[0], acy = an[1], aw = an[2], ah = an[3];
        float bcx = dx * aw + acx;
        float bcy = dy * ah + acy;
        float bw = aw * expf(dw);
        float bh = ah * expf(dh);
        float pa = (float)bb - 90.0f;
        float th = pa * (float)0.017453292519943295;
        float cth = cosf(th), sth = sinf(th);
        float hw2 = bw * 0.5f, hh2 = bh * 0.5f;
        const float oxs[4] = {1.0f, -1.0f, -1.0f, 1.0f};
        const float oys[4] = {1.0f, 1.0f, -1.0f, -1.0f};
        for (int q = 0; q < 4; ++q) {
            float ox = oxs[q] * hw2, oy = oys[q] * hh2;
            cor[base * 8 + 2 * q]     = bcx + ox * cth - oy * sth;
            cor[base * 8 + 2 * q + 1] = bcy + ox * sth + oy * cth;
        }
        val[base] = 1;
        sc[base] = sqrtf(topv);
        lab[base] = cl + 1;
        area[base] = bw * bh;
        ccx[base] = bcx; ccy[base] = bcy;
        crad[base] = 0.5f * sqrtf(bw * bw + bh * bh);
    }
}

// ---- register-resident dynamic-index helpers (avoid scratch) ----
__device__ __forceinline__ float arr_get8(const float* a, int idx) {
    float r = a[0];
#pragma unroll
    for (int s = 1; s < 8; ++s) r = (s == idx) ? a[s] : r;
    return r;
}
__device__ __forceinline__ void arr_set8(float* a, int idx, float v) {
#pragma unroll
    for (int s = 0; s < 8; ++s) a[s] = (s == idx) ? v : a[s];
}

// ---------------- rotated-quad intersection (Sutherland-Hodgman, mirrors ref) ----
__device__ float quad_inter_area(const float* c1x, const float* c1y,
                                 const float* c2x, const float* c2y) {
#pragma clang fp contract(off)
    float px[8], py[8], qx[8], qy[8];
    int n = 4;
#pragma unroll
    for (int i = 0; i < 8; ++i) { px[i] = (i < 4) ? c1x[i] : 0.0f;
                                  py[i] = (i < 4) ? c1y[i] : 0.0f;
                                  qx[i] = 0.0f; qy[i] = 0.0f; }
#pragma unroll
    for (int e = 0; e < 4; ++e) {
        float p1x = c2x[e], p1y = c2y[e];
        int e2 = (e + 1) & 3;
        float ex = c2x[e2] - p1x, ey = c2y[e2] - p1y;
        int m = 0;
#pragma unroll
        for (int i = 0; i < 8; ++i) {
            if (i < n) {
                int j = (i == n - 1) ? 0 : i + 1;
                float cxi = px[i], cyi = py[i];
                float cxj = arr_get8(px, j), cyj = arr_get8(py, j);
                float dc = ex * (cyi - p1y) - ey * (cxi - p1x);
                float dn = ex * (cyj - p1y) - ey * (cxj - p1x);
                bool ic = (dc >= 0.0f), in2 = (dn >= 0.0f);
                if (ic) { arr_set8(qx, m, cxi); arr_set8(qy, m, cyi); ++m; }
                if (ic != in2) {
                    float denom = dc - dn;
                    if (fabsf(denom) < 1e-8f) denom = 1e-8f;
                    float tp = dc / denom;
                    arr_set8(qx, m, cxi + tp * (cxj - cxi));
                    arr_set8(qy, m, cyi + tp * (cyj - cyi));
                    ++m;
                }
            }
        }
        n = m;
        if (n == 0) return 0.0f;
#pragma unroll
        for (int i = 0; i < 8; ++i) { px[i] = qx[i]; py[i] = qy[i]; }
    }
    float ssum = 0.0f;
#pragma unroll
    for (int i = 0; i < 8; ++i) {
        if (i < n) {
            int j = (i == n - 1) ? 0 : i + 1;
            ssum += px[i] * arr_get8(py, j) - arr_get8(px, j) * py[i];
        }
    }
    return 0.5f * fabsf(ssum);
}

// ---------------- K4: fused pairs(IoU->LDS bits) + greedy NMS + output ----------------
__global__ __launch_bounds__(512)
void k_pairnms(const float* __restrict__ cor, const float* __restrict__ area,
               const int* __restrict__ lab,
               const float* __restrict__ ccx, const float* __restrict__ ccy,
               const float* __restrict__ crad,
               const int* __restrict__ val, const float* __restrict__ sc,
               float* __restrict__ out) {
#pragma clang fp contract(off)
    const int n = blockIdx.x;
    const int tid = threadIdx.x;
    __shared__ unsigned int supL[7 * 7 * 64];   // low 32 row-bits
    __shared__ unsigned int supH[7 * 7 * 64];   // high 32 row-bits
    __shared__ int order[POSTN];
    for (int z = tid; z < 7 * 7 * 64; z += 512) { supL[z] = 0u; supH[z] = 0u; }
    __syncthreads();
    const int base = n * KTOP;
    const int wid = tid >> 6, lane = tid & 63;
    // pair phase: wave per row i (row loads are wave-uniform -> scalar)
    for (int i = wid; i < KTOP; i += 8) {
        const int li = lab[base + i];
        if (li != 0) {
            const float xi = ccx[base + i], yi = ccy[base + i];
            const float ri = crad[base + i], ai = area[base + i];
            float cix[4], ciy[4];
            for (int q = 0; q < 4; ++q) {
                cix[q] = cor[(base + i) * 8 + 2 * q];
                ciy[q] = cor[(base + i) * 8 + 2 * q + 1];
            }
            for (int j = i + 1 + lane; j < KTOP; j += 64) {
                if (lab[base + j] != li) continue;
                float dx = xi - ccx[base + j];
                float dy = yi - ccy[base + j];
                float rr = ri + crad[base + j];
                if (dx * dx + dy * dy > rr * rr) continue;   // disjoint -> iou==0
                float cjx[4], cjy[4];
                for (int q = 0; q < 4; ++q) {
                    cjx[q] = cor[(base + j) * 8 + 2 * q];
                    cjy[q] = cor[(base + j) * 8 + 2 * q + 1];
                }
                float inter = quad_inter_area(cix, ciy, cjx, cjy);
                float iou = inter / (ai + area[base + j] - inter + 1e-7f);
                if (iou > 0.4f) {
                    int sidx = ((j >> 6) * 7 + (i >> 6)) * 64 + (j & 63);
                    if ((i & 63) < 32) atomicOr(&supL[sidx], 1u << (i & 31));
                    else               atomicOr(&supH[sidx], 1u << (i & 31));
                }
            }
        }
    }
    __syncthreads();
    // wave 0: register-resident greedy scan (verbatim semantics) + output
    if (tid < 64) {
        const int l = tid;
        unsigned removed = 0;
#pragma unroll
        for (int t = 0; t < 7; ++t) {
            int r = 64 * t + l;
            int v = (r < KTOP) ? val[base + r] : 0;
            if (!v) removed |= (1u << t);
        }
#pragma unroll
        for (int rb = 0; rb < 7; ++rb) {
            unsigned long long cmr[7];
#pragma unroll
            for (int t = 0; t < 7; ++t) {
                int sidx = (t * 7 + rb) * 64 + l;
                cmr[t] = ((unsigned long long)supH[sidx] << 32) |
                         (unsigned long long)supL[sidx];
            }
            const int lim = (rb == 6) ? (KTOP - 384) : 64;
            for (int ib = 0; ib < lim; ++ib) {
                unsigned rm = (unsigned)__builtin_amdgcn_readlane((int)removed, ib);
                if (!((rm >> rb) & 1u)) {
                    removed |= ((unsigned)((cmr[0] >> ib) & 1ULL));
                    removed |= ((unsigned)((cmr[1] >> ib) & 1ULL)) << 1;
                    removed |= ((unsigned)((cmr[2] >> ib) & 1ULL)) << 2;
                    removed |= ((unsigned)((cmr[3] >> ib) & 1ULL)) << 3;
                    removed |= ((unsigned)((cmr[4] >> ib) & 1ULL)) << 4;
                    removed |= ((unsigned)((cmr[5] >> ib) & 1ULL)) << 5;
                    removed |= ((unsigned)((cmr[6] >> ib) & 1ULL)) << 6;
                }
            }
        }
        // rank kept candidates in index order, collect first 100
        int rank = 0;
#pragma unroll
        for (int t = 0; t < 7; ++t) {
            bool kb = !((removed >> t) & 1u) && (64 * t + l < KTOP);
            unsigned long long m = __ballot(kb);
            int my = rank + __popcll(m & ((1ULL << l) - 1ULL));
            if (kb && my < POSTN) order[my] = 64 * t + l;
            rank += __popcll(m);
        }
        int kcnt = rank < POSTN ? rank : POSTN;
        __threadfence_block();   // order[] visibility within the wave
        for (int e = l; e < POSTN * 11; e += 64) {
            int r = e / 11, c = e - r * 11;
            float v = 0.0f;
            if (r < kcnt) {
                int i = order[r];
                int b = base + i;
                if (c < 8)       v = cor[b * 8 + c];
                else if (c == 8) v = sc[b];
                else if (c == 9) v = (float)lab[b];
                else             v = 1.0f;
            }
            out[(n * POSTN + r) * 11 + c] = v;
        }
    }
}

extern "C" void kernel_launch(void* const* d_in, const int* in_sizes, int n_in,
                              void* d_out, int out_size, void* d_ws, size_t ws_size,
                              hipStream_t stream) {
    const float* box_cls = (const float*)d_in[0];
    const float* box_reg = (const float*)d_in[1];
    const float* ctr     = (const float*)d_in[2];
    const float* ang     = (const float*)d_in[3];
    const float* anchors = (const float*)d_in[4];
    float* out = (float*)d_out;
    char* ws = (char*)d_ws;

    int* cnt_blk = (int*)(ws + CNTB_OFF);
    unsigned long long* skey  = (unsigned long long*)(ws + SKEY_OFF);
    unsigned long long* stage = (unsigned long long*)(ws + STAGE_OFF);
    float* cor  = (float*)(ws + COR_OFF);
    float* area = (float*)(ws + AREA_OFF);
    int* lab    = (int*)(ws + LAB_OFF);
    float* sc   = (float*)(ws + SC_OFF);
    int* val    = (int*)(ws + VAL_OFF);
    float* ccx  = (float*)(ws + CCX_OFF);
    float* ccy  = (float*)(ws + CCY_OFF);
    float* crad = (float*)(ws + CRAD_OFF);

    k_hist    <<<dim3(NBLK, NIMG), 256, 0, stream>>>(box_cls, ctr, cnt_blk, stage);
    k_selstage<<<NIMG, 256, 0, stream>>>(stage, cnt_blk, box_cls, ctr, skey);
    k_decode  <<<dim3(KTOP, NIMG), 64, 0, stream>>>(skey, box_reg, ang, anchors,
                                                    cor, area, lab, sc, val,
                                                    ccx, ccy, crad);
    k_pairnms <<<NIMG, 512, 0, stream>>>(cor, area, lab, ccx, ccy, crad,
                                         val, sc, out);
}

// Round 5
// 244.125 us; speedup vs baseline: 1.2890x; 1.2890x over previous
//
#include <hip/hip_runtime.h>
#include <math.h>

#define NIMG 4
#define NCLS 15
#define HW 65536
#define NANG 90
#define KTOP 400
#define POSTN 100
#define NBINS 4096
#define CAP 4096
#define NBLK 128            // k_hist blocks per image
#define SBUF 512            // per-block stage buffer (expected ~92 entries/block)
#define FLOOR_VAL (1434.0f / 4096.0f)   // bit-exact: comb >= 1434/4096  <=>  bin >= 1434

// ---- workspace layout (bytes); NO pre-zeroing needed ----
// supT zeroed by k_decode; cnt_blk fully written by k_hist; rest fully written.
#define CNTB_OFF   0                      // 4*128*4 = 2048
#define SKEY_OFF   2048                   // 4*400*8 = 12800
#define COR_OFF    14848                  // 4*400*8*4 = 51200
#define AREA_OFF   66048                  // 6400 each below
#define LAB_OFF    72448
#define SC_OFF     78848
#define VAL_OFF    85248
#define CCX_OFF    91648
#define CCY_OFF    98048
#define CRAD_OFF   104448
#define SUPT_OFF   110848                 // 4*7*7*64*8 = 100352
#define STAGE_OFF  211200                 // 4*128*512*8 = 2 MB -> ends 2308352

__device__ __forceinline__ float sigmoidf(float x) {
    return 1.0f / (1.0f + expf(-x));
}

// ---------------- K1: stage candidates with comb >= FLOOR into block-private regions ----
// (round-4 verified) No histogram, no global atomics, no pre-zeroed state.
__global__ __launch_bounds__(256)
void k_hist(const float* __restrict__ cls, const float* __restrict__ ctr,
            int* __restrict__ cnt_blk, unsigned long long* __restrict__ stage) {
    __shared__ unsigned long long sbuf[SBUF];
    __shared__ int scount;
    const int n = blockIdx.y;
    const int bx = blockIdx.x;
    const int p2 = (bx * 256 + threadIdx.x) * 2;
    if (threadIdx.x == 0) scount = 0;
    __syncthreads();
    float2 cv2 = *(const float2*)(ctr + n * HW + p2);
    float cv[2] = {sigmoidf(cv2.x), sigmoidf(cv2.y)};
    for (int j = 0; j < NCLS; ++j) {
        float2 s2 = *(const float2*)(cls + (size_t)(n * NCLS + j) * HW + p2);
        float sv[2] = {s2.x, s2.y};
#pragma unroll
        for (int e = 0; e < 2; ++e) {
            float s = sigmoidf(sv[e]);
            float comb = s * cv[e];
            if (comb >= FLOOR_VAL) {          // implies s > 0.05 (comb <= s)
                int m = atomicAdd(&scount, 1);
                if (m < SBUF) {
                    unsigned int fb  = __float_as_uint(comb);
                    unsigned int idx = (unsigned int)((p2 + e) * NCLS + j);
                    sbuf[m] = ((unsigned long long)fb << 32) |
                              (unsigned long long)(~idx);
                }
            }
        }
    }
    __syncthreads();
    int c = scount;
    int cc = c > SBUF ? SBUF : c;
    if (threadIdx.x == 0)
        cnt_blk[n * NBLK + bx] = (c > SBUF) ? (cc | (1 << 31)) : cc;
    unsigned long long* rp = stage + (size_t)(n * NBLK + bx) * SBUF;
    for (int m = threadIdx.x; m < cc; m += 256) rp[m] = sbuf[m];
}

// ---------------- K2: staged histogram -> exact threshold -> filter -> bitonic top-400 ---
// (round-4 verified) 1 block per image. Fallback full-rescan path for correctness.
__global__ __launch_bounds__(256)
void k_selstage(const unsigned long long* __restrict__ stage,
                const int* __restrict__ cnt_blk,
                const float* __restrict__ cls, const float* __restrict__ ctr,
                unsigned long long* __restrict__ skey) {
    const int n = blockIdx.x;
    __shared__ unsigned long long key[CAP];    // 32 KB
    __shared__ int hist[NBINS];                // 16 KB
    __shared__ int cbc[NBLK];
    __shared__ int part[256];
    __shared__ int s_t, s_c, s_tot, s_ovf;
    const int tid = threadIdx.x;
    if (tid == 0) { s_t = 0; s_c = 0; s_tot = 0; s_ovf = 0; }
    for (int b = tid; b < NBINS; b += 256) hist[b] = 0;
    __syncthreads();
    if (tid < NBLK) {
        int v = cnt_blk[n * NBLK + tid];
        int c = v & 0x7fffffff;
        cbc[tid] = c;
        atomicAdd(&s_tot, c);
        if (v < 0) atomicOr(&s_ovf, 1);
    }
    __syncthreads();
    const int r  = tid >> 1;                   // region 0..127 (2 threads per region)
    const int m0 = tid & 1;
    const bool fb = (s_ovf != 0) || (s_tot < KTOP);
    if (!fb) {
        // staged hist == full hist above FLOOR; total >= 400 guarantees exact t >= FLOOR
        const unsigned long long* rp = stage + (size_t)(n * NBLK + r) * SBUF;
        const int c = cbc[r];
        for (int m = m0; m < c; m += 2) {
            float comb = __uint_as_float((unsigned int)(rp[m] >> 32));
            int b = (int)(comb * 4096.0f);
            b = b < 0 ? 0 : (b > NBINS - 1 ? NBINS - 1 : b);
            atomicAdd(&hist[b], 1);
        }
    } else {
        // fallback: full histogram of image n (never taken on healthy margins)
        for (int j = 0; j < NCLS; ++j) {
            for (int pos = tid; pos < HW; pos += 256) {
                float s = sigmoidf(cls[(size_t)(n * NCLS + j) * HW + pos]);
                if (s > 0.05f) {
                    float comb = s * sigmoidf(ctr[n * HW + pos]);
                    int b = (int)(comb * 4096.0f);
                    b = b < 0 ? 0 : (b > NBINS - 1 ? NBINS - 1 : b);
                    atomicAdd(&hist[b], 1);
                }
            }
        }
    }
    __syncthreads();
    // exact threshold via segment suffix-scan
    {
        int s = 0;
        int base = tid * 16;
        for (int b = 0; b < 16; ++b) s += hist[base + b];
        part[tid] = s;
        __syncthreads();
        for (int off = 1; off < 256; off <<= 1) {
            int v = part[tid] + ((tid + off < 256) ? part[tid + off] : 0);
            __syncthreads();
            part[tid] = v;
            __syncthreads();
        }
        int sg = tid;
        int suf = part[sg];
        int above = (sg == 255) ? 0 : part[sg + 1];
        if (suf >= KTOP && above < KTOP) {
            int a2 = above, t = sg * 16;
            for (int b = sg * 16 + 15; b >= sg * 16; --b) {
                a2 += hist[b];
                if (a2 >= KTOP) { t = b; break; }
            }
            s_t = t;            // exactly one thread writes
        }
        __syncthreads();
    }
    const int t = s_t;
    if (!fb) {
        const unsigned long long* rp = stage + (size_t)(n * NBLK + r) * SBUF;
        const int c = cbc[r];
        for (int m = m0; m < c; m += 2) {
            unsigned long long kk = rp[m];
            float comb = __uint_as_float((unsigned int)(kk >> 32));
            int b = (int)(comb * 4096.0f);
            b = b < 0 ? 0 : (b > NBINS - 1 ? NBINS - 1 : b);
            if (b >= t) {
                int pos = atomicAdd(&s_c, 1);
                if (pos < CAP) key[pos] = kk;
            }
        }
    } else {
        for (int j = 0; j < NCLS; ++j) {
            for (int pos = tid; pos < HW; pos += 256) {
                float s = sigmoidf(cls[(size_t)(n * NCLS + j) * HW + pos]);
                if (s > 0.05f) {
                    float comb = s * sigmoidf(ctr[n * HW + pos]);
                    int b = (int)(comb * 4096.0f);
                    b = b < 0 ? 0 : (b > NBINS - 1 ? NBINS - 1 : b);
                    if (b >= t) {
                        int pos2 = atomicAdd(&s_c, 1);
                        if (pos2 < CAP) {
                            unsigned int fbits = __float_as_uint(comb);
                            unsigned int idx = (unsigned int)(pos * NCLS + j);
                            key[pos2] = ((unsigned long long)fbits << 32) |
                                        (unsigned long long)(~idx);
                        }
                    }
                }
            }
        }
    }
    __syncthreads();
    int c = s_c;
    if (c > CAP) c = CAP;
    int S = 512;
    while (S < c) S <<= 1;
    for (int i = tid; i < S; i += 256)
        if (i >= c) key[i] = 0ULL;
    __syncthreads();
    for (int k = 2; k <= S; k <<= 1) {
        for (int j = k >> 1; j > 0; j >>= 1) {
            for (int i = tid; i < S; i += 256) {
                int l = i ^ j;
                if (l > i) {
                    unsigned long long a = key[i], b = key[l];
                    bool up = ((i & k) == 0);
                    if ((a > b) == up) { key[i] = b; key[l] = a; }
                }
            }
            __syncthreads();
        }
    }
    for (int r2 = tid; r2 < KTOP; r2 += 256)
        skey[n * KTOP + r2] = key[S - 1 - r2];
}

// ---------------- K3: per-candidate decode (one wave each) + supT zeroing ----------
// (round-3 verified: absmax 0.0 with this exact supT-zeroing scheme)
__global__ __launch_bounds__(64)
void k_decode(const unsigned long long* __restrict__ skey,
              const float* __restrict__ reg, const float* __restrict__ ang,
              const float* __restrict__ anchors,
              float* __restrict__ cor, float* __restrict__ area, int* __restrict__ lab,
              float* __restrict__ sc, int* __restrict__ val,
              float* __restrict__ ccx, float* __restrict__ ccy, float* __restrict__ crad,
              unsigned long long* __restrict__ supT) {
#pragma clang fp contract(off)
    const int r = blockIdx.x;
    const int n = blockIdx.y;
    const int l = threadIdx.x;
    // zero supT slice (4*7*7*64 = 12544 u64 over 1600 blocks x 8)
    {
        int bid = n * KTOP + r;
        int z = bid * 8 + l;
        if (l < 8 && z < 12544) supT[z] = 0ULL;
    }
    const int base = n * KTOP + r;
    unsigned long long kk = skey[base];
    if (kk == 0ULL) {
        if (l == 0) {
            val[base] = 0; sc[base] = 0.0f; lab[base] = 0; area[base] = 0.0f;
            ccx[base] = 0.0f; ccy[base] = 0.0f; crad[base] = 0.0f;
            for (int q = 0; q < 8; ++q) cor[base * 8 + q] = 0.0f;
        }
        return;
    }
    unsigned int idx = ~((unsigned int)kk);
    int loc = (int)(idx / 15u);
    // angle argmax (first max) across the wave
    const float* ap = ang + ((size_t)n * NANG) * HW + loc;
    float bv = -INFINITY; int bb = 1000;
    for (int b = l; b < NANG; b += 64) {
        float v = ap[(size_t)b * HW];
        if (v > bv) { bv = v; bb = b; }   // b ascending per lane: keeps first max
    }
    for (int off = 32; off > 0; off >>= 1) {
        float ov = __shfl_down(bv, off);
        int   ob = __shfl_down(bb, off);
        if (ov > bv || (ov == bv && ob < bb)) { bv = ov; bb = ob; }
    }
    if (l == 0) {
        int cl = (int)(idx % 15u);
        float topv = __uint_as_float((unsigned int)(kk >> 32));
        const float* rp = reg + ((size_t)n * 4) * HW + loc;
        float dx = rp[0] / 10.0f;
        float dy = rp[HW] / 10.0f;
        float dw = rp[2 * (size_t)HW] / 5.0f;
        float dh = rp[3 * (size_t)HW] / 5.0f;
        dw = fminf(fmaxf(dw, -10.0f), 4.0f);
        dh = fminf(fmaxf(dh, -10.0f), 4.0f);
        const float* an = anchors + ((size_t)n * HW + loc) * 5;
        float acx = an[0], acy = an[1], aw = an[2], ah = an[3];
        float bcx = dx * aw + acx;
        float bcy = dy * ah + acy;
        float bw = aw * expf(dw);
        float bh = ah * expf(dh);
        float pa = (float)bb - 90.0f;
        float th = pa * (float)0.017453292519943295;
        float cth = cosf(th), sth = sinf(th);
        float hw2 = bw * 0.5f, hh2 = bh * 0.5f;
        const float oxs[4] = {1.0f, -1.0f, -1.0f, 1.0f};
        const float oys[4] = {1.0f, 1.0f, -1.0f, -1.0f};
        for (int q = 0; q < 4; ++q) {
            float ox = oxs[q] * hw2, oy = oys[q] * hh2;
            cor[base * 8 + 2 * q]     = bcx + ox * cth - oy * sth;
            cor[base * 8 + 2 * q + 1] = bcy + ox * sth + oy * cth;
        }
        val[base] = 1;
        sc[base] = sqrtf(topv);
        lab[base] = cl + 1;
        area[base] = bw * bh;
        ccx[base] = bcx; ccy[base] = bcy;
        crad[base] = 0.5f * sqrtf(bw * bw + bh * bh);
    }
}

// ---- register-resident dynamic-index helpers (avoid scratch) ----
__device__ __forceinline__ float arr_get8(const float* a, int idx) {
    float r = a[0];
#pragma unroll
    for (int s = 1; s < 8; ++s) r = (s == idx) ? a[s] : r;
    return r;
}
__device__ __forceinline__ void arr_set8(float* a, int idx, float v) {
#pragma unroll
    for (int s = 0; s < 8; ++s) a[s] = (s == idx) ? v : a[s];
}

// ---------------- rotated-quad intersection (Sutherland-Hodgman, mirrors ref) ----
__device__ float quad_inter_area(const float* c1x, const float* c1y,
                                 const float* c2x, const float* c2y) {
#pragma clang fp contract(off)
    float px[8], py[8], qx[8], qy[8];
    int n = 4;
#pragma unroll
    for (int i = 0; i < 8; ++i) { px[i] = (i < 4) ? c1x[i] : 0.0f;
                                  py[i] = (i < 4) ? c1y[i] : 0.0f;
                                  qx[i] = 0.0f; qy[i] = 0.0f; }
#pragma unroll
    for (int e = 0; e < 4; ++e) {
        float p1x = c2x[e], p1y = c2y[e];
        int e2 = (e + 1) & 3;
        float ex = c2x[e2] - p1x, ey = c2y[e2] - p1y;
        int m = 0;
#pragma unroll
        for (int i = 0; i < 8; ++i) {
            if (i < n) {
                int j = (i == n - 1) ? 0 : i + 1;
                float cxi = px[i], cyi = py[i];
                float cxj = arr_get8(px, j), cyj = arr_get8(py, j);
                float dc = ex * (cyi - p1y) - ey * (cxi - p1x);
                float dn = ex * (cyj - p1y) - ey * (cxj - p1x);
                bool ic = (dc >= 0.0f), in2 = (dn >= 0.0f);
                if (ic) { arr_set8(qx, m, cxi); arr_set8(qy, m, cyi); ++m; }
                if (ic != in2) {
                    float denom = dc - dn;
                    if (fabsf(denom) < 1e-8f) denom = 1e-8f;
                    float tp = dc / denom;
                    arr_set8(qx, m, cxi + tp * (cxj - cxi));
                    arr_set8(qy, m, cyi + tp * (cyj - cyi));
                    ++m;
                }
            }
        }
        n = m;
        if (n == 0) return 0.0f;
#pragma unroll
        for (int i = 0; i < 8; ++i) { px[i] = qx[i]; py[i] = qy[i]; }
    }
    float ssum = 0.0f;
#pragma unroll
    for (int i = 0; i < 8; ++i) {
        if (i < n) {
            int j = (i == n - 1) ? 0 : i + 1;
            ssum += px[i] * arr_get8(py, j) - arr_get8(px, j) * py[i];
        }
    }
    return 0.5f * fabsf(ssum);
}

// ---------------- K4: fused prefilter + IoU -> transposed suppress bits ----------------
// (round-0 verified; thread-per-pair, whole-GPU parallelism for the VALU-heavy clips)
__global__ __launch_bounds__(256)
void k_pairs(const float* __restrict__ cor, const float* __restrict__ area,
             const int* __restrict__ lab,
             const float* __restrict__ ccx, const float* __restrict__ ccy,
             const float* __restrict__ crad,
             unsigned long long* __restrict__ supT) {
#pragma clang fp contract(off)
    const int n = blockIdx.y;
    const int p = blockIdx.x * 256 + threadIdx.x;
    if (p >= KTOP * KTOP) return;
    const int i = p / KTOP;
    const int j = p - i * KTOP;
    if (j <= i) return;
    const int base = n * KTOP;
    const int li = lab[base + i];
    if (li == 0 || lab[base + j] != li) return;
    float dx = ccx[base + i] - ccx[base + j];
    float dy = ccy[base + i] - ccy[base + j];
    float rr = crad[base + i] + crad[base + j];
    if (dx * dx + dy * dy > rr * rr) return;   // provably disjoint -> inter==0 -> iou==0
    float cix[4], ciy[4], cjx[4], cjy[4];
    for (int q = 0; q < 4; ++q) {
        cix[q] = cor[(base + i) * 8 + 2 * q]; ciy[q] = cor[(base + i) * 8 + 2 * q + 1];
        cjx[q] = cor[(base + j) * 8 + 2 * q]; cjy[q] = cor[(base + j) * 8 + 2 * q + 1];
    }
    float inter = quad_inter_area(cix, ciy, cjx, cjy);
    float iou = inter / (area[base + i] + area[base + j] - inter + 1e-7f);
    if (iou > 0.4f) {
        // row i suppresses column j: bit (i&63) of supT[n][j>>6][i>>6][j&63]
        atomicOr(&supT[((size_t)(n * 7 + (j >> 6)) * 7 + (i >> 6)) * 64 + (j & 63)],
                 1ULL << (i & 63));
    }
}

// ---------------- K5: single-wave register-resident greedy NMS + output ----------------
// (round-0 verified)
__global__ __launch_bounds__(64)
void k_nms_out(const unsigned long long* __restrict__ supT,
               const int* __restrict__ val,
               const float* __restrict__ cor, const float* __restrict__ sc,
               const int* __restrict__ lab, float* __restrict__ out) {
    const int n = blockIdx.x;
    const int l = threadIdx.x;
    // lane l owns columns (candidates) l, l+64, ..., l+384; bit t of `removed`
    unsigned removed = 0;
#pragma unroll
    for (int t = 0; t < 7; ++t) {
        int r = 64 * t + l;
        int v = (r < KTOP) ? val[n * KTOP + r] : 0;
        if (!v) removed |= (1u << t);
    }
    // cm[t][rb] bit ib = row (64*rb+ib) suppresses col (64*t+l)
    unsigned long long cm[7][7];
#pragma unroll
    for (int t = 0; t < 7; ++t)
#pragma unroll
        for (int rb = 0; rb < 7; ++rb)
            cm[t][rb] = supT[((size_t)(n * 7 + t) * 7 + rb) * 64 + l];
    // serial greedy scan, all in registers
#pragma unroll
    for (int rb = 0; rb < 7; ++rb) {
        const int lim = (rb == 6) ? (KTOP - 384) : 64;
        for (int ib = 0; ib < lim; ++ib) {
            unsigned rm = (unsigned)__builtin_amdgcn_readlane((int)removed, ib);
            if (!((rm >> rb) & 1u)) {   // candidate 64*rb+ib kept -> apply its suppressions
                removed |= ((unsigned)((cm[0][rb] >> ib) & 1ULL));
                removed |= ((unsigned)((cm[1][rb] >> ib) & 1ULL)) << 1;
                removed |= ((unsigned)((cm[2][rb] >> ib) & 1ULL)) << 2;
                removed |= ((unsigned)((cm[3][rb] >> ib) & 1ULL)) << 3;
                removed |= ((unsigned)((cm[4][rb] >> ib) & 1ULL)) << 4;
                removed |= ((unsigned)((cm[5][rb] >> ib) & 1ULL)) << 5;
                removed |= ((unsigned)((cm[6][rb] >> ib) & 1ULL)) << 6;
            }
        }
    }
    // rank kept candidates in index order, collect first 100
    __shared__ int order[POSTN];
    int rank = 0;
#pragma unroll
    for (int t = 0; t < 7; ++t) {
        bool kb = !((removed >> t) & 1u) && (64 * t + l < KTOP);
        unsigned long long m = __ballot(kb);
        int my = rank + __popcll(m & ((1ULL << l) - 1ULL));
        if (kb && my < POSTN) order[my] = 64 * t + l;
        rank += __popcll(m);
    }
    int kcnt = rank < POSTN ? rank : POSTN;
    __syncthreads();   // single wave: cheap; makes order[] visible
    for (int e = l; e < POSTN * 11; e += 64) {
        int r = e / 11, c = e - r * 11;
        float v = 0.0f;
        if (r < kcnt) {
            int i = order[r];
            int b = n * KTOP + i;
            if (c < 8)       v = cor[b * 8 + c];
            else if (c == 8) v = sc[b];
            else if (c == 9) v = (float)lab[b];
            else             v = 1.0f;
        }
        out[(n * POSTN + r) * 11 + c] = v;
    }
}

extern "C" void kernel_launch(void* const* d_in, const int* in_sizes, int n_in,
                              void* d_out, int out_size, void* d_ws, size_t ws_size,
                              hipStream_t stream) {
    const float* box_cls = (const float*)d_in[0];
    const float* box_reg = (const float*)d_in[1];
    const float* ctr     = (const float*)d_in[2];
    const float* ang     = (const float*)d_in[3];
    const float* anchors = (const float*)d_in[4];
    float* out = (float*)d_out;
    char* ws = (char*)d_ws;

    int* cnt_blk = (int*)(ws + CNTB_OFF);
    unsigned long long* skey  = (unsigned long long*)(ws + SKEY_OFF);
    unsigned long long* supT  = (unsigned long long*)(ws + SUPT_OFF);
    unsigned long long* stage = (unsigned long long*)(ws + STAGE_OFF);
    float* cor  = (float*)(ws + COR_OFF);
    float* area = (float*)(ws + AREA_OFF);
    int* lab    = (int*)(ws + LAB_OFF);
    float* sc   = (float*)(ws + SC_OFF);
    int* val    = (int*)(ws + VAL_OFF);
    float* ccx  = (float*)(ws + CCX_OFF);
    float* ccy  = (float*)(ws + CCY_OFF);
    float* crad = (float*)(ws + CRAD_OFF);

    k_hist    <<<dim3(NBLK, NIMG), 256, 0, stream>>>(box_cls, ctr, cnt_blk, stage);
    k_selstage<<<NIMG, 256, 0, stream>>>(stage, cnt_blk, box_cls, ctr, skey);
    k_decode  <<<dim3(KTOP, NIMG), 64, 0, stream>>>(skey, box_reg, ang, anchors,
                                                    cor, area, lab, sc, val,
                                                    ccx, ccy, crad, supT);
    k_pairs   <<<dim3((KTOP * KTOP + 255) / 256, NIMG), 256, 0, stream>>>(
                  cor, area, lab, ccx, ccy, crad, supT);
    k_nms_out <<<NIMG, 64, 0, stream>>>(supT, val, cor, sc, lab, out);
}